// Round 1
// baseline (331.755 us; speedup 1.0000x reference)
//
#include <hip/hip_runtime.h>

// ---------------------------------------------------------------------------
// Channel_Transformer_WGCNLayer  (B=16, N=1024, C=512)  -- bf16 MFMA pipeline
// All GEMMs: C[M,Nc] = A[M,K] @ Bt[Nc,K]^T  (K contiguous on both operands)
// ---------------------------------------------------------------------------

typedef __bf16 bf16x8 __attribute__((ext_vector_type(8)));
typedef float  f32x4  __attribute__((ext_vector_type(4)));

#define DEV __device__ __forceinline__

DEV float bf2f(unsigned short u) {
  union { unsigned i; float f; } x; x.i = ((unsigned)u) << 16; return x.f;
}
DEV unsigned short f2bf(float f) {           // round-to-nearest-even
  unsigned u = __float_as_uint(f);
  u += 0x7fffu + ((u >> 16) & 1u);
  return (unsigned short)(u >> 16);
}
DEV float sigmoidf_(float x) { return 1.0f / (1.0f + __expf(-x)); }

DEV float wave_sum(float v) {
#pragma unroll
  for (int o = 32; o > 0; o >>= 1) v += __shfl_xor(v, o, 64);
  return v;
}
DEV float wave_max(float v) {
#pragma unroll
  for (int o = 32; o > 0; o >>= 1) v = fmaxf(v, __shfl_xor(v, o, 64));
  return v;
}

// ---------------------------- f32 -> bf16 cast -----------------------------
__global__ __launch_bounds__(256) void cast_kernel(const float* __restrict__ in,
                                                   unsigned short* __restrict__ out,
                                                   int n4) {
  int g = blockIdx.x * 256 + threadIdx.x;
  if (g >= n4) return;
  float4 v = *(const float4*)(in + (size_t)g * 4);
  ushort4 o;
  o.x = f2bf(v.x); o.y = f2bf(v.y); o.z = f2bf(v.z); o.w = f2bf(v.w);
  *(ushort4*)(out + (size_t)g * 4) = o;
}

// ------------------- degree: d_is[b,n] = rsqrt(sum_m adj*sig) --------------
__global__ __launch_bounds__(256) void sigrow_kernel(const float* __restrict__ adj,
                                                     const float* __restrict__ edge,
                                                     float* __restrict__ dis) {
  __shared__ float sh[4];
  size_t row = blockIdx.x;                 // b*1024 + n
  int n = (int)(row & 1023);
  const float* ar = adj + row * 1024;
  const float* er = edge + (size_t)n * 1024;
  int c = threadIdx.x * 4;
  float4 a4 = *(const float4*)(ar + c);
  float4 e4 = *(const float4*)(er + c);
  float s = a4.x * sigmoidf_(e4.x) + a4.y * sigmoidf_(e4.y) +
            a4.z * sigmoidf_(e4.z) + a4.w * sigmoidf_(e4.w);
  s = wave_sum(s);
  if ((threadIdx.x & 63) == 0) sh[threadIdx.x >> 6] = s;
  __syncthreads();
  if (threadIdx.x == 0) {
    float t = sh[0] + sh[1] + sh[2] + sh[3];
    dis[row] = t > 0.0f ? rsqrtf(t) : 0.0f;
  }
}

// -------------- W_A_norm[b,n,m] = d[n]*adj*sig(edge)*d[m] -> bf16 ----------
__global__ __launch_bounds__(256) void wa_kernel(const float* __restrict__ adj,
                                                 const float* __restrict__ edge,
                                                 const float* __restrict__ dis,
                                                 unsigned short* __restrict__ wa) {
  size_t g = (size_t)blockIdx.x * 256 + threadIdx.x;   // group of 4 along m
  int m = (int)(g & 255) * 4;
  size_t rest = g >> 8;                                // b*1024 + n
  int n = (int)(rest & 1023);
  int b = (int)(rest >> 10);
  float4 a4 = *(const float4*)(adj + rest * 1024 + m);
  float4 e4 = *(const float4*)(edge + (size_t)n * 1024 + m);
  float dn = dis[rest];
  float4 dm = *(const float4*)(dis + (size_t)b * 1024 + m);
  ushort4 o;
  o.x = f2bf(dn * a4.x * sigmoidf_(e4.x) * dm.x);
  o.y = f2bf(dn * a4.y * sigmoidf_(e4.y) * dm.y);
  o.z = f2bf(dn * a4.z * sigmoidf_(e4.z) * dm.z);
  o.w = f2bf(dn * a4.w * sigmoidf_(e4.w) * dm.w);
  *(ushort4*)(wa + g * 4) = o;
}

// --------------------------- LayerNorm over rows ---------------------------
template <int VPT, bool OUTF32>
__global__ __launch_bounds__(256) void ln_kernel(const unsigned short* __restrict__ in,
                                                 const float* __restrict__ gw,
                                                 const float* __restrict__ gb,
                                                 void* __restrict__ out, int D) {
  __shared__ float sh[8];
  size_t row = blockIdx.x;
  const unsigned short* x = in + row * (size_t)D;
  int base = threadIdx.x * VPT;
  float v[VPT];
  if (VPT == 4) {
    ushort4 u = *(const ushort4*)(x + base);
    v[0] = bf2f(u.x); v[1] = bf2f(u.y); v[2] = bf2f(u.z); v[3] = bf2f(u.w);
  } else {
    ushort2 u = *(const ushort2*)(x + base);
    v[0] = bf2f(u.x); v[1] = bf2f(u.y);
  }
  float s = 0.f, sq = 0.f;
#pragma unroll
  for (int i = 0; i < VPT; i++) { s += v[i]; sq += v[i] * v[i]; }
  s = wave_sum(s); sq = wave_sum(sq);
  if ((threadIdx.x & 63) == 0) { sh[threadIdx.x >> 6] = s; sh[4 + (threadIdx.x >> 6)] = sq; }
  __syncthreads();
  s = sh[0] + sh[1] + sh[2] + sh[3];
  sq = sh[4] + sh[5] + sh[6] + sh[7];
  float mean = s / D;
  float var = sq / D - mean * mean;
  float rs = rsqrtf(fmaxf(var, 0.0f) + 1e-5f);
#pragma unroll
  for (int i = 0; i < VPT; i++) {
    float y = (v[i] - mean) * rs * gw[base + i] + gb[base + i];
    if (OUTF32) ((float*)out)[row * D + base + i] = y;
    else        ((unsigned short*)out)[row * D + base + i] = f2bf(y);
  }
}

// ------------------------- softmax over rows of 512 ------------------------
__global__ __launch_bounds__(256) void softmax_kernel(const float* __restrict__ in,
                                                      unsigned short* __restrict__ out) {
  __shared__ float sh[4];
  size_t row = blockIdx.x;
  const float* x = in + row * 512;
  float2 u = *(const float2*)(x + threadIdx.x * 2);
  float a = u.x * 0.03125f, b = u.y * 0.03125f;   // channel_scale = 1024^-0.5
  float m = wave_max(fmaxf(a, b));
  int wid = threadIdx.x >> 6;
  if ((threadIdx.x & 63) == 0) sh[wid] = m;
  __syncthreads();
  m = fmaxf(fmaxf(sh[0], sh[1]), fmaxf(sh[2], sh[3]));
  __syncthreads();
  float e0 = __expf(a - m), e1 = __expf(b - m);
  float s = wave_sum(e0 + e1);
  if ((threadIdx.x & 63) == 0) sh[wid] = s;
  __syncthreads();
  s = sh[0] + sh[1] + sh[2] + sh[3];
  float inv = 1.0f / s;
  ushort2 o; o.x = f2bf(e0 * inv); o.y = f2bf(e1 * inv);
  *(ushort2*)(out + row * 512 + threadIdx.x * 2) = o;
}

// ---------------- bf16 MFMA GEMM: C = A[M,K] @ Bt[Nc,K]^T ------------------
// 64x64 tile, 4 waves (each 32x32 via 2x2 16x16x32 MFMA frags), padded LDS.
template <int BIAS /*0 none,1 row,2 col*/, bool LEAKY, bool RESID, bool OUTF32>
__global__ __launch_bounds__(256) void gemm_bt(
    const unsigned short* __restrict__ A, size_t sA,
    const unsigned short* __restrict__ Bt, size_t sB,
    const float* __restrict__ bias,
    const unsigned short* __restrict__ resid,
    void* __restrict__ out, int M, int Nc, int K) {
  __shared__ unsigned short As[64][40];   // +8 pad: 2-way bank alias only
  __shared__ unsigned short Bs[64][40];
  const int b = blockIdx.z;
  const unsigned short* Ab = A + sA * b;
  const unsigned short* Bb = Bt + sB * b;
  const int tM = blockIdx.y * 64, tN = blockIdx.x * 64;
  const int tid = threadIdx.x;
  const int wid = tid >> 6, lane = tid & 63;
  const int wr = wid >> 1, wc = wid & 1;
  const int l15 = lane & 15, l4 = lane >> 4;
  const int lrow = tid >> 2, lcol = (tid & 3) * 8;
  f32x4 acc[2][2] = {};
  for (int k0 = 0; k0 < K; k0 += 32) {
    *(bf16x8*)&As[lrow][lcol] = *(const bf16x8*)(Ab + (size_t)(tM + lrow) * K + k0 + lcol);
    *(bf16x8*)&Bs[lrow][lcol] = *(const bf16x8*)(Bb + (size_t)(tN + lrow) * K + k0 + lcol);
    __syncthreads();
    bf16x8 a0 = *(const bf16x8*)&As[wr * 32 + l15][l4 * 8];
    bf16x8 a1 = *(const bf16x8*)&As[wr * 32 + 16 + l15][l4 * 8];
    bf16x8 b0 = *(const bf16x8*)&Bs[wc * 32 + l15][l4 * 8];
    bf16x8 b1 = *(const bf16x8*)&Bs[wc * 32 + 16 + l15][l4 * 8];
    acc[0][0] = __builtin_amdgcn_mfma_f32_16x16x32_bf16(a0, b0, acc[0][0], 0, 0, 0);
    acc[0][1] = __builtin_amdgcn_mfma_f32_16x16x32_bf16(a0, b1, acc[0][1], 0, 0, 0);
    acc[1][0] = __builtin_amdgcn_mfma_f32_16x16x32_bf16(a1, b0, acc[1][0], 0, 0, 0);
    acc[1][1] = __builtin_amdgcn_mfma_f32_16x16x32_bf16(a1, b1, acc[1][1], 0, 0, 0);
    __syncthreads();
  }
  const size_t ob = (size_t)M * Nc * b;
#pragma unroll
  for (int i = 0; i < 2; i++)
#pragma unroll
    for (int j = 0; j < 2; j++) {
      const int cg = tN + wc * 32 + j * 16 + l15;
      const int rbase = tM + wr * 32 + i * 16 + l4 * 4;
#pragma unroll
      for (int r = 0; r < 4; r++) {
        const int rg = rbase + r;
        float v = acc[i][j][r];
        if (BIAS == 1) v += bias[rg];
        if (BIAS == 2) v += bias[cg];
        if (LEAKY) v = v > 0.0f ? v : 0.01f * v;
        const size_t idx = ob + (size_t)rg * Nc + cg;
        if (RESID) v += bf2f(resid[idx]);
        if (OUTF32) ((float*)out)[idx] = v;
        else        ((unsigned short*)out)[idx] = f2bf(v);
      }
    }
}

// ---------------------------------------------------------------------------
extern "C" void kernel_launch(void* const* d_in, const int* in_sizes, int n_in,
                              void* d_out, int out_size, void* d_ws, size_t ws_size,
                              hipStream_t stream) {
  const float* node_feats = (const float*)d_in[0];   // [16,1024,512]
  const float* adj        = (const float*)d_in[1];   // [16,1024,1024]
  const float* linear_w   = (const float*)d_in[2];   // [512,512]
  const float* linear_b   = (const float*)d_in[3];   // [512]
  const float* q_w        = (const float*)d_in[4];   // [1024,1024]
  const float* q_b        = (const float*)d_in[5];
  const float* k_w        = (const float*)d_in[6];
  const float* k_b        = (const float*)d_in[7];
  const float* v_w        = (const float*)d_in[8];
  const float* v_b        = (const float*)d_in[9];
  const float* n1w        = (const float*)d_in[10];  // [1024]
  const float* n1b        = (const float*)d_in[11];
  const float* n2w        = (const float*)d_in[12];  // [512]
  const float* n2b        = (const float*)d_in[13];
  const float* edge       = (const float*)d_in[14];  // [1024,1024]
  float* out = (float*)d_out;

  const int B = 16, N = 1024, C = 512;
  const size_t MiB = 1u << 20;
  char* w = (char*)d_ws;
  // lifetime-aliased workspace layout (total ~119.1 MiB)
  unsigned short* nf_bf   = (unsigned short*)(w);             // 16 MiB [dies after G1]
  unsigned short* Xt_bf   = (unsigned short*)(w + 16 * MiB);  // 16 MiB [dies after LN1]
  float*          att_raw = (float*)(w);                      // 16 MiB (reuses nf)
  unsigned short* WA_bf   = (unsigned short*)(w);             // 32 MiB (reuses nf+Xt, after softmax)
  unsigned short* Txln    = (unsigned short*)(w + 32 * MiB);  // 16 MiB
  unsigned short* q_bf    = (unsigned short*)(w + 48 * MiB);  // 16 MiB [dies after Gatt]
  unsigned short* X3_bf   = (unsigned short*)(w + 48 * MiB);  // 16 MiB (reuses q)
  unsigned short* k_bf    = (unsigned short*)(w + 64 * MiB);  // 16 MiB [dies after Gatt]
  unsigned short* att_bf  = (unsigned short*)(w + 64 * MiB);  //  8 MiB (reuses k)
  unsigned short* vt_bf   = (unsigned short*)(w + 80 * MiB);  // 16 MiB
  unsigned short* Tx2_bf  = (unsigned short*)(w + 96 * MiB);  // 16 MiB
  unsigned short* lw_bf   = (unsigned short*)(w + 112 * MiB); // 0.5 MiB
  unsigned short* qw_bf   = (unsigned short*)(w + 113 * MiB); // 2 MiB
  unsigned short* kw_bf   = (unsigned short*)(w + 115 * MiB); // 2 MiB
  unsigned short* vw_bf   = (unsigned short*)(w + 117 * MiB); // 2 MiB
  float*          dis     = (float*)(w + 119 * MiB);          // 64 KiB

  // casts to bf16
  cast_kernel<<<(B * N * C / 4 + 255) / 256, 256, 0, stream>>>(node_feats, nf_bf, B * N * C / 4);
  cast_kernel<<<(C * C / 4 + 255) / 256, 256, 0, stream>>>(linear_w, lw_bf, C * C / 4);
  cast_kernel<<<(N * N / 4 + 255) / 256, 256, 0, stream>>>(q_w, qw_bf, N * N / 4);
  cast_kernel<<<(N * N / 4 + 255) / 256, 256, 0, stream>>>(k_w, kw_bf, N * N / 4);
  cast_kernel<<<(N * N / 4 + 255) / 256, 256, 0, stream>>>(v_w, vw_bf, N * N / 4);

  // degree normalization factors
  sigrow_kernel<<<B * N, 256, 0, stream>>>(adj, edge, dis);

  // G1: Xt[b,o,n] = leaky(lw @ nf^T + lb[o])   M=C, Nc=N, K=C
  gemm_bt<1, true, false, false><<<dim3(N / 64, C / 64, B), 256, 0, stream>>>(
      lw_bf, 0, nf_bf, (size_t)N * C, linear_b, nullptr, Xt_bf, C, N, C);

  // LN1 over n (D=1024) -> Txln bf16
  ln_kernel<4, false><<<B * C, 256, 0, stream>>>(Xt_bf, n1w, n1b, Txln, N);

  // q,k: [b,x,g] = Txln @ {q,k}_w^T + b[g]     M=C, Nc=N, K=N
  gemm_bt<2, false, false, false><<<dim3(N / 64, C / 64, B), 256, 0, stream>>>(
      Txln, (size_t)C * N, qw_bf, 0, q_b, nullptr, q_bf, C, N, N);
  gemm_bt<2, false, false, false><<<dim3(N / 64, C / 64, B), 256, 0, stream>>>(
      Txln, (size_t)C * N, kw_bf, 0, k_b, nullptr, k_bf, C, N, N);

  // v^T: vt[b,g,x] = leaky(v_w @ Txln^T + v_b[g])   M=N, Nc=C, K=N
  gemm_bt<1, true, false, false><<<dim3(C / 64, N / 64, B), 256, 0, stream>>>(
      vw_bf, 0, Txln, (size_t)C * N, v_b, nullptr, vt_bf, N, C, N);

  // att_raw[b,x,y] = q @ k^T   M=C, Nc=C, K=N   (f32 out)
  gemm_bt<0, false, false, true><<<dim3(C / 64, C / 64, B), 256, 0, stream>>>(
      q_bf, (size_t)C * N, k_bf, (size_t)C * N, nullptr, nullptr, att_raw, C, C, N);

  // softmax(att_raw * 1/32) -> att_bf
  softmax_kernel<<<B * C, 256, 0, stream>>>(att_raw, att_bf);

  // W_A normalized bf16 (overwrites bytes [0,32MiB): nf/att_raw/Xt all dead)
  wa_kernel<<<B * N * N / 4 / 256, 256, 0, stream>>>(adj, edge, dis, WA_bf);

  // Tx2[b,x,h] = Txln + att @ v    M=C, Nc=N, K=C   (Bt = vt[h,y])
  gemm_bt<0, false, true, false><<<dim3(N / 64, C / 64, B), 256, 0, stream>>>(
      att_bf, (size_t)C * C, vt_bf, (size_t)N * C, nullptr, Txln, Tx2_bf, C, N, C);

  // X3[b,n,o] = W_A @ X2          M=N, Nc=C, K=N   (Bt = Tx2[o,m])
  gemm_bt<0, false, false, false><<<dim3(C / 64, N / 64, B), 256, 0, stream>>>(
      WA_bf, (size_t)N * N, Tx2_bf, (size_t)C * N, nullptr, nullptr, X3_bf, N, C, N);

  // final LN over o (D=512) -> f32 out
  ln_kernel<2, true><<<B * N, 256, 0, stream>>>(X3_bf, n2w, n2b, out, C);
}

// Round 2
// 280.507 us; speedup vs baseline: 1.1827x; 1.1827x over previous
//
#include <hip/hip_runtime.h>

// ---------------------------------------------------------------------------
// Channel_Transformer_WGCNLayer  (B=16, N=1024, C=512)  -- bf16 MFMA pipeline
// All GEMMs: C[M,Nc] = A[M,K] @ Bt[Nc,K]^T  (K contiguous on both operands)
// GEMM structure: m97-verified 128x128 tile, BK=32, global_load_lds width=16
// ---------------------------------------------------------------------------

typedef __bf16 bf16x8 __attribute__((ext_vector_type(8)));
typedef float  f32x4  __attribute__((ext_vector_type(4)));

#define DEV __device__ __forceinline__

DEV float bf2f(unsigned short u) {
  union { unsigned i; float f; } x; x.i = ((unsigned)u) << 16; return x.f;
}
DEV unsigned short f2bf(float f) {           // round-to-nearest-even
  unsigned u = __float_as_uint(f);
  u += 0x7fffu + ((u >> 16) & 1u);
  return (unsigned short)(u >> 16);
}
DEV float sigmoidf_(float x) { return 1.0f / (1.0f + __expf(-x)); }

DEV float wave_sum(float v) {
#pragma unroll
  for (int o = 32; o > 0; o >>= 1) v += __shfl_xor(v, o, 64);
  return v;
}
DEV float wave_max(float v) {
#pragma unroll
  for (int o = 32; o > 0; o >>= 1) v = fmaxf(v, __shfl_xor(v, o, 64));
  return v;
}

// async global->LDS, 16B per lane; lds dest must be wave-uniform (HW adds lane*16)
DEV void gload16(const unsigned short* g, unsigned short* l) {
  __builtin_amdgcn_global_load_lds(
      (const __attribute__((address_space(1))) unsigned int*)g,
      (__attribute__((address_space(3))) unsigned int*)l, 16, 0, 0);
}

// ---------------------------- f32 -> bf16 cast -----------------------------
__global__ __launch_bounds__(256) void cast_kernel(const float* __restrict__ in,
                                                   unsigned short* __restrict__ out,
                                                   int n4) {
  int g = blockIdx.x * 256 + threadIdx.x;
  if (g >= n4) return;
  float4 v = *(const float4*)(in + (size_t)g * 4);
  ushort4 o;
  o.x = f2bf(v.x); o.y = f2bf(v.y); o.z = f2bf(v.z); o.w = f2bf(v.w);
  *(ushort4*)(out + (size_t)g * 4) = o;
}

// ------------------- degree: d_is[b,n] = rsqrt(sum_m adj*sig) --------------
__global__ __launch_bounds__(256) void sigrow_kernel(const float* __restrict__ adj,
                                                     const float* __restrict__ edge,
                                                     float* __restrict__ dis) {
  __shared__ float sh[4];
  size_t row = blockIdx.x;                 // b*1024 + n
  int n = (int)(row & 1023);
  const float* ar = adj + row * 1024;
  const float* er = edge + (size_t)n * 1024;
  int c = threadIdx.x * 4;
  float4 a4 = *(const float4*)(ar + c);
  float4 e4 = *(const float4*)(er + c);
  float s = a4.x * sigmoidf_(e4.x) + a4.y * sigmoidf_(e4.y) +
            a4.z * sigmoidf_(e4.z) + a4.w * sigmoidf_(e4.w);
  s = wave_sum(s);
  if ((threadIdx.x & 63) == 0) sh[threadIdx.x >> 6] = s;
  __syncthreads();
  if (threadIdx.x == 0) {
    float t = sh[0] + sh[1] + sh[2] + sh[3];
    dis[row] = t > 0.0f ? rsqrtf(t) : 0.0f;
  }
}

// -------------- W_A_norm[b,n,m] = d[n]*adj*sig(edge)*d[m] -> bf16 ----------
__global__ __launch_bounds__(256) void wa_kernel(const float* __restrict__ adj,
                                                 const float* __restrict__ edge,
                                                 const float* __restrict__ dis,
                                                 unsigned short* __restrict__ wa) {
  size_t g = (size_t)blockIdx.x * 256 + threadIdx.x;   // group of 4 along m
  int m = (int)(g & 255) * 4;
  size_t rest = g >> 8;                                // b*1024 + n
  int n = (int)(rest & 1023);
  int b = (int)(rest >> 10);
  float4 a4 = *(const float4*)(adj + rest * 1024 + m);
  float4 e4 = *(const float4*)(edge + (size_t)n * 1024 + m);
  float dn = dis[rest];
  float4 dm = *(const float4*)(dis + (size_t)b * 1024 + m);
  ushort4 o;
  o.x = f2bf(dn * a4.x * sigmoidf_(e4.x) * dm.x);
  o.y = f2bf(dn * a4.y * sigmoidf_(e4.y) * dm.y);
  o.z = f2bf(dn * a4.z * sigmoidf_(e4.z) * dm.z);
  o.w = f2bf(dn * a4.w * sigmoidf_(e4.w) * dm.w);
  *(ushort4*)(wa + g * 4) = o;
}

// --------------------------- LayerNorm over rows ---------------------------
template <int VPT, bool OUTF32>
__global__ __launch_bounds__(256) void ln_kernel(const unsigned short* __restrict__ in,
                                                 const float* __restrict__ gw,
                                                 const float* __restrict__ gb,
                                                 void* __restrict__ out, int D) {
  __shared__ float sh[8];
  size_t row = blockIdx.x;
  const unsigned short* x = in + row * (size_t)D;
  int base = threadIdx.x * VPT;
  float v[VPT];
  if (VPT == 4) {
    ushort4 u = *(const ushort4*)(x + base);
    v[0] = bf2f(u.x); v[1] = bf2f(u.y); v[2] = bf2f(u.z); v[3] = bf2f(u.w);
  } else {
    ushort2 u = *(const ushort2*)(x + base);
    v[0] = bf2f(u.x); v[1] = bf2f(u.y);
  }
  float s = 0.f, sq = 0.f;
#pragma unroll
  for (int i = 0; i < VPT; i++) { s += v[i]; sq += v[i] * v[i]; }
  s = wave_sum(s); sq = wave_sum(sq);
  if ((threadIdx.x & 63) == 0) { sh[threadIdx.x >> 6] = s; sh[4 + (threadIdx.x >> 6)] = sq; }
  __syncthreads();
  s = sh[0] + sh[1] + sh[2] + sh[3];
  sq = sh[4] + sh[5] + sh[6] + sh[7];
  float mean = s / D;
  float var = sq / D - mean * mean;
  float rs = rsqrtf(fmaxf(var, 0.0f) + 1e-5f);
#pragma unroll
  for (int i = 0; i < VPT; i++) {
    float y = (v[i] - mean) * rs * gw[base + i] + gb[base + i];
    if (OUTF32) ((float*)out)[row * D + base + i] = y;
    else        ((unsigned short*)out)[row * D + base + i] = f2bf(y);
  }
}

// ------------------------- softmax over rows of 512 ------------------------
__global__ __launch_bounds__(256) void softmax_kernel(const float* __restrict__ in,
                                                      unsigned short* __restrict__ out) {
  __shared__ float sh[4];
  size_t row = blockIdx.x;
  const float* x = in + row * 512;
  float2 u = *(const float2*)(x + threadIdx.x * 2);
  float a = u.x * 0.03125f, b = u.y * 0.03125f;   // channel_scale = 1024^-0.5
  float m = wave_max(fmaxf(a, b));
  int wid = threadIdx.x >> 6;
  if ((threadIdx.x & 63) == 0) sh[wid] = m;
  __syncthreads();
  m = fmaxf(fmaxf(sh[0], sh[1]), fmaxf(sh[2], sh[3]));
  __syncthreads();
  float e0 = __expf(a - m), e1 = __expf(b - m);
  float s = wave_sum(e0 + e1);
  if ((threadIdx.x & 63) == 0) sh[wid] = s;
  __syncthreads();
  s = sh[0] + sh[1] + sh[2] + sh[3];
  float inv = 1.0f / s;
  ushort2 o; o.x = f2bf(e0 * inv); o.y = f2bf(e1 * inv);
  *(ushort2*)(out + row * 512 + threadIdx.x * 2) = o;
}

// ---------------- bf16 MFMA GEMM: C = A[M,K] @ Bt[Nc,K]^T ------------------
// m97 structure: 128x128 tile, BK=32, 4 waves (each 64x64 = 4x4 16x16x32
// frags), linear LDS [128][32], global_load_lds width=16 staging.
template <int BIAS /*0 none,1 row,2 col*/, bool LEAKY, bool RESID, bool OUTF32>
__global__ __launch_bounds__(256) void gemm_bt(
    const unsigned short* __restrict__ A, size_t sA,
    const unsigned short* __restrict__ Bt, size_t sB,
    const float* __restrict__ bias,
    const unsigned short* __restrict__ resid,
    void* __restrict__ out, int M, int Nc, int K) {
  __shared__ unsigned short As[128 * 32];   // linear: row*32 + col, 64B rows
  __shared__ unsigned short Bs[128 * 32];
  const int b = blockIdx.z;
  const unsigned short* Ab = A + sA * b;
  const unsigned short* Bb = Bt + sB * b;
  const int tM = blockIdx.y * 128, tN = blockIdx.x * 128;
  const int tid = threadIdx.x;
  const int wid = tid >> 6, lane = tid & 63;
  const int wr = wid >> 1, wc = wid & 1;
  const int l15 = lane & 15, l4 = lane >> 4;
  // staging: wave w covers rows [w*16, w*16+16) (+64 for 2nd issue);
  // lane l -> row w*16 + (l>>2), col (l&3)*8  (matches HW's base + lane*16B)
  const int srow = wid * 16 + (lane >> 2);
  const int scol = (lane & 3) * 8;
  const unsigned short* gA = Ab + (size_t)(tM + srow) * K + scol;
  const unsigned short* gB = Bb + (size_t)(tN + srow) * K + scol;
  unsigned short* lA = As + wid * 512;      // wave-uniform LDS base (1KB/wave)
  unsigned short* lB = Bs + wid * 512;
  const size_t rowskip = (size_t)64 * K;

  f32x4 acc[4][4] = {};
  for (int k0 = 0; k0 < K; k0 += 32) {
    gload16(gA + k0, lA);
    gload16(gA + k0 + rowskip, lA + 2048);
    gload16(gB + k0, lB);
    gload16(gB + k0 + rowskip, lB + 2048);
    __syncthreads();                        // drains vmcnt before use
    bf16x8 af[4], bg[4];
#pragma unroll
    for (int i = 0; i < 4; i++) {
      af[i] = *(const bf16x8*)&As[(wr * 64 + i * 16 + l15) * 32 + l4 * 8];
      bg[i] = *(const bf16x8*)&Bs[(wc * 64 + i * 16 + l15) * 32 + l4 * 8];
    }
#pragma unroll
    for (int i = 0; i < 4; i++)
#pragma unroll
      for (int j = 0; j < 4; j++)
        acc[i][j] = __builtin_amdgcn_mfma_f32_16x16x32_bf16(af[i], bg[j], acc[i][j], 0, 0, 0);
    __syncthreads();
  }

  const size_t ob = (size_t)M * Nc * b;
#pragma unroll
  for (int i = 0; i < 4; i++)
#pragma unroll
    for (int j = 0; j < 4; j++) {
      const int cg = tN + wc * 64 + j * 16 + l15;
      const int rbase = tM + wr * 64 + i * 16 + l4 * 4;
#pragma unroll
      for (int r = 0; r < 4; r++) {
        const int rg = rbase + r;
        float v = acc[i][j][r];
        if (BIAS == 1) v += bias[rg];
        if (BIAS == 2) v += bias[cg];
        if (LEAKY) v = v > 0.0f ? v : 0.01f * v;
        const size_t idx = ob + (size_t)rg * Nc + cg;
        if (RESID) v += bf2f(resid[idx]);
        if (OUTF32) ((float*)out)[idx] = v;
        else        ((unsigned short*)out)[idx] = f2bf(v);
      }
    }
}

// ---------------------------------------------------------------------------
extern "C" void kernel_launch(void* const* d_in, const int* in_sizes, int n_in,
                              void* d_out, int out_size, void* d_ws, size_t ws_size,
                              hipStream_t stream) {
  const float* node_feats = (const float*)d_in[0];   // [16,1024,512]
  const float* adj        = (const float*)d_in[1];   // [16,1024,1024]
  const float* linear_w   = (const float*)d_in[2];   // [512,512]
  const float* linear_b   = (const float*)d_in[3];   // [512]
  const float* q_w        = (const float*)d_in[4];   // [1024,1024]
  const float* q_b        = (const float*)d_in[5];
  const float* k_w        = (const float*)d_in[6];
  const float* k_b        = (const float*)d_in[7];
  const float* v_w        = (const float*)d_in[8];
  const float* v_b        = (const float*)d_in[9];
  const float* n1w        = (const float*)d_in[10];  // [1024]
  const float* n1b        = (const float*)d_in[11];
  const float* n2w        = (const float*)d_in[12];  // [512]
  const float* n2b        = (const float*)d_in[13];
  const float* edge       = (const float*)d_in[14];  // [1024,1024]
  float* out = (float*)d_out;

  const int B = 16, N = 1024, C = 512;
  const size_t MiB = 1u << 20;
  char* w = (char*)d_ws;
  // lifetime-aliased workspace layout (total ~119.1 MiB)
  unsigned short* nf_bf   = (unsigned short*)(w);             // 16 MiB [dies after G1]
  unsigned short* Xt_bf   = (unsigned short*)(w + 16 * MiB);  // 16 MiB [dies after LN1]
  float*          att_raw = (float*)(w);                      // 16 MiB (reuses nf)
  unsigned short* WA_bf   = (unsigned short*)(w);             // 32 MiB (reuses nf+Xt, after softmax)
  unsigned short* Txln    = (unsigned short*)(w + 32 * MiB);  // 16 MiB
  unsigned short* q_bf    = (unsigned short*)(w + 48 * MiB);  // 16 MiB [dies after Gatt]
  unsigned short* X3_bf   = (unsigned short*)(w + 48 * MiB);  // 16 MiB (reuses q)
  unsigned short* k_bf    = (unsigned short*)(w + 64 * MiB);  // 16 MiB [dies after Gatt]
  unsigned short* att_bf  = (unsigned short*)(w + 64 * MiB);  //  8 MiB (reuses k)
  unsigned short* vt_bf   = (unsigned short*)(w + 80 * MiB);  // 16 MiB
  unsigned short* Tx2_bf  = (unsigned short*)(w + 96 * MiB);  // 16 MiB
  unsigned short* lw_bf   = (unsigned short*)(w + 112 * MiB); // 0.5 MiB
  unsigned short* qw_bf   = (unsigned short*)(w + 113 * MiB); // 2 MiB
  unsigned short* kw_bf   = (unsigned short*)(w + 115 * MiB); // 2 MiB
  unsigned short* vw_bf   = (unsigned short*)(w + 117 * MiB); // 2 MiB
  float*          dis     = (float*)(w + 119 * MiB);          // 64 KiB

  // casts to bf16
  cast_kernel<<<(B * N * C / 4 + 255) / 256, 256, 0, stream>>>(node_feats, nf_bf, B * N * C / 4);
  cast_kernel<<<(C * C / 4 + 255) / 256, 256, 0, stream>>>(linear_w, lw_bf, C * C / 4);
  cast_kernel<<<(N * N / 4 + 255) / 256, 256, 0, stream>>>(q_w, qw_bf, N * N / 4);
  cast_kernel<<<(N * N / 4 + 255) / 256, 256, 0, stream>>>(k_w, kw_bf, N * N / 4);
  cast_kernel<<<(N * N / 4 + 255) / 256, 256, 0, stream>>>(v_w, vw_bf, N * N / 4);

  // degree normalization factors
  sigrow_kernel<<<B * N, 256, 0, stream>>>(adj, edge, dis);

  // G1: Xt[b,o,n] = leaky(lw @ nf^T + lb[o])   M=C, Nc=N, K=C
  gemm_bt<1, true, false, false><<<dim3(N / 128, C / 128, B), 256, 0, stream>>>(
      lw_bf, 0, nf_bf, (size_t)N * C, linear_b, nullptr, Xt_bf, C, N, C);

  // LN1 over n (D=1024) -> Txln bf16
  ln_kernel<4, false><<<B * C, 256, 0, stream>>>(Xt_bf, n1w, n1b, Txln, N);

  // q,k: [b,x,g] = Txln @ {q,k}_w^T + b[g]     M=C, Nc=N, K=N
  gemm_bt<2, false, false, false><<<dim3(N / 128, C / 128, B), 256, 0, stream>>>(
      Txln, (size_t)C * N, qw_bf, 0, q_b, nullptr, q_bf, C, N, N);
  gemm_bt<2, false, false, false><<<dim3(N / 128, C / 128, B), 256, 0, stream>>>(
      Txln, (size_t)C * N, kw_bf, 0, k_b, nullptr, k_bf, C, N, N);

  // v^T: vt[b,g,x] = leaky(v_w @ Txln^T + v_b[g])   M=N, Nc=C, K=N
  gemm_bt<1, true, false, false><<<dim3(C / 128, N / 128, B), 256, 0, stream>>>(
      vw_bf, 0, Txln, (size_t)C * N, v_b, nullptr, vt_bf, N, C, N);

  // att_raw[b,x,y] = q @ k^T   M=C, Nc=C, K=N   (f32 out)
  gemm_bt<0, false, false, true><<<dim3(C / 128, C / 128, B), 256, 0, stream>>>(
      q_bf, (size_t)C * N, k_bf, (size_t)C * N, nullptr, nullptr, att_raw, C, C, N);

  // softmax(att_raw * 1/32) -> att_bf
  softmax_kernel<<<B * C, 256, 0, stream>>>(att_raw, att_bf);

  // W_A normalized bf16 (overwrites bytes [0,32MiB): nf/att_raw/Xt all dead)
  wa_kernel<<<B * N * N / 4 / 256, 256, 0, stream>>>(adj, edge, dis, WA_bf);

  // Tx2[b,x,h] = Txln + att @ v    M=C, Nc=N, K=C   (Bt = vt[h,y])
  gemm_bt<0, false, true, false><<<dim3(N / 128, C / 128, B), 256, 0, stream>>>(
      att_bf, (size_t)C * C, vt_bf, (size_t)N * C, nullptr, Txln, Tx2_bf, C, N, C);

  // X3[b,n,o] = W_A @ X2          M=N, Nc=C, K=N   (Bt = Tx2[o,m])
  gemm_bt<0, false, false, false><<<dim3(C / 128, N / 128, B), 256, 0, stream>>>(
      WA_bf, (size_t)N * N, Tx2_bf, (size_t)C * N, nullptr, nullptr, X3_bf, N, C, N);

  // final LN over o (D=512) -> f32 out
  ln_kernel<2, true><<<B * N, 256, 0, stream>>>(X3_bf, n2w, n2b, out, C);
}

// Round 3
// 267.302 us; speedup vs baseline: 1.2411x; 1.0494x over previous
//
#include <hip/hip_runtime.h>

// ---------------------------------------------------------------------------
// Channel_Transformer_WGCNLayer  (B=16, N=1024, C=512)  -- bf16 MFMA pipeline
// All GEMMs: C[M,Nc] = A[M,K] @ Bt[Nc,K]^T  (K contiguous on both operands)
// GEMM: m97 128x128 tile, BK=32, global_load_lds w=16, XCD-chunked swizzle.
// q&k fused into one Nc=2048 dispatch (qw/kw adjacent in workspace).
// ---------------------------------------------------------------------------

typedef __bf16 bf16x8 __attribute__((ext_vector_type(8)));
typedef float  f32x4  __attribute__((ext_vector_type(4)));

#define DEV __device__ __forceinline__

DEV float bf2f(unsigned short u) {
  union { unsigned i; float f; } x; x.i = ((unsigned)u) << 16; return x.f;
}
DEV unsigned short f2bf(float f) {           // round-to-nearest-even
  unsigned u = __float_as_uint(f);
  u += 0x7fffu + ((u >> 16) & 1u);
  return (unsigned short)(u >> 16);
}
DEV float sigmoidf_(float x) { return 1.0f / (1.0f + __expf(-x)); }

DEV float wave_sum(float v) {
#pragma unroll
  for (int o = 32; o > 0; o >>= 1) v += __shfl_xor(v, o, 64);
  return v;
}
DEV float wave_max(float v) {
#pragma unroll
  for (int o = 32; o > 0; o >>= 1) v = fmaxf(v, __shfl_xor(v, o, 64));
  return v;
}

// async global->LDS, 16B per lane; lds dest is wave-uniform (HW adds lane*16)
DEV void gload16(const unsigned short* g, unsigned short* l) {
  __builtin_amdgcn_global_load_lds(
      (const __attribute__((address_space(1))) unsigned int*)g,
      (__attribute__((address_space(3))) unsigned int*)l, 16, 0, 0);
}

// ---------------------------- f32 -> bf16 cast -----------------------------
__global__ __launch_bounds__(256) void cast_kernel(const float* __restrict__ in,
                                                   unsigned short* __restrict__ out,
                                                   int n4) {
  int g = blockIdx.x * 256 + threadIdx.x;
  if (g >= n4) return;
  float4 v = *(const float4*)(in + (size_t)g * 4);
  ushort4 o;
  o.x = f2bf(v.x); o.y = f2bf(v.y); o.z = f2bf(v.z); o.w = f2bf(v.w);
  *(ushort4*)(out + (size_t)g * 4) = o;
}

// ------------------- degree: d_is[b,n] = rsqrt(sum_m adj*sig) --------------
__global__ __launch_bounds__(256) void sigrow_kernel(const float* __restrict__ adj,
                                                     const float* __restrict__ edge,
                                                     float* __restrict__ dis) {
  __shared__ float sh[4];
  size_t row = blockIdx.x;                 // b*1024 + n
  int n = (int)(row & 1023);
  const float* ar = adj + row * 1024;
  const float* er = edge + (size_t)n * 1024;
  int c = threadIdx.x * 4;
  float4 a4 = *(const float4*)(ar + c);
  float4 e4 = *(const float4*)(er + c);
  float s = a4.x * sigmoidf_(e4.x) + a4.y * sigmoidf_(e4.y) +
            a4.z * sigmoidf_(e4.z) + a4.w * sigmoidf_(e4.w);
  s = wave_sum(s);
  if ((threadIdx.x & 63) == 0) sh[threadIdx.x >> 6] = s;
  __syncthreads();
  if (threadIdx.x == 0) {
    float t = sh[0] + sh[1] + sh[2] + sh[3];
    dis[row] = t > 0.0f ? rsqrtf(t) : 0.0f;
  }
}

// -------------- W_A_norm[b,n,m] = d[n]*adj*sig(edge)*d[m] -> bf16 ----------
__global__ __launch_bounds__(256) void wa_kernel(const float* __restrict__ adj,
                                                 const float* __restrict__ edge,
                                                 const float* __restrict__ dis,
                                                 unsigned short* __restrict__ wa) {
  size_t g = (size_t)blockIdx.x * 256 + threadIdx.x;   // group of 4 along m
  int m = (int)(g & 255) * 4;
  size_t rest = g >> 8;                                // b*1024 + n
  int n = (int)(rest & 1023);
  int b = (int)(rest >> 10);
  float4 a4 = *(const float4*)(adj + rest * 1024 + m);
  float4 e4 = *(const float4*)(edge + (size_t)n * 1024 + m);
  float dn = dis[rest];
  float4 dm = *(const float4*)(dis + (size_t)b * 1024 + m);
  ushort4 o;
  o.x = f2bf(dn * a4.x * sigmoidf_(e4.x) * dm.x);
  o.y = f2bf(dn * a4.y * sigmoidf_(e4.y) * dm.y);
  o.z = f2bf(dn * a4.z * sigmoidf_(e4.z) * dm.z);
  o.w = f2bf(dn * a4.w * sigmoidf_(e4.w) * dm.w);
  *(ushort4*)(wa + g * 4) = o;
}

// --------------------------- LayerNorm over rows ---------------------------
template <int VPT, bool OUTF32>
__global__ __launch_bounds__(256) void ln_kernel(const unsigned short* __restrict__ in,
                                                 const float* __restrict__ gw,
                                                 const float* __restrict__ gb,
                                                 void* __restrict__ out, int D) {
  __shared__ float sh[8];
  size_t row = blockIdx.x;
  const unsigned short* x = in + row * (size_t)D;
  int base = threadIdx.x * VPT;
  float v[VPT];
  if (VPT == 4) {
    ushort4 u = *(const ushort4*)(x + base);
    v[0] = bf2f(u.x); v[1] = bf2f(u.y); v[2] = bf2f(u.z); v[3] = bf2f(u.w);
  } else {
    ushort2 u = *(const ushort2*)(x + base);
    v[0] = bf2f(u.x); v[1] = bf2f(u.y);
  }
  float s = 0.f, sq = 0.f;
#pragma unroll
  for (int i = 0; i < VPT; i++) { s += v[i]; sq += v[i] * v[i]; }
  s = wave_sum(s); sq = wave_sum(sq);
  if ((threadIdx.x & 63) == 0) { sh[threadIdx.x >> 6] = s; sh[4 + (threadIdx.x >> 6)] = sq; }
  __syncthreads();
  s = sh[0] + sh[1] + sh[2] + sh[3];
  sq = sh[4] + sh[5] + sh[6] + sh[7];
  float mean = s / D;
  float var = sq / D - mean * mean;
  float rs = rsqrtf(fmaxf(var, 0.0f) + 1e-5f);
#pragma unroll
  for (int i = 0; i < VPT; i++) {
    float y = (v[i] - mean) * rs * gw[base + i] + gb[base + i];
    if (OUTF32) ((float*)out)[row * D + base + i] = y;
    else        ((unsigned short*)out)[row * D + base + i] = f2bf(y);
  }
}

// ------------------------- softmax over rows of 512 ------------------------
__global__ __launch_bounds__(256) void softmax_kernel(const float* __restrict__ in,
                                                      unsigned short* __restrict__ out) {
  __shared__ float sh[4];
  size_t row = blockIdx.x;
  const float* x = in + row * 512;
  float2 u = *(const float2*)(x + threadIdx.x * 2);
  float a = u.x * 0.03125f, b = u.y * 0.03125f;   // channel_scale = 1024^-0.5
  float m = wave_max(fmaxf(a, b));
  int wid = threadIdx.x >> 6;
  if ((threadIdx.x & 63) == 0) sh[wid] = m;
  __syncthreads();
  m = fmaxf(fmaxf(sh[0], sh[1]), fmaxf(sh[2], sh[3]));
  __syncthreads();
  float e0 = __expf(a - m), e1 = __expf(b - m);
  float s = wave_sum(e0 + e1);
  if ((threadIdx.x & 63) == 0) sh[wid] = s;
  __syncthreads();
  s = sh[0] + sh[1] + sh[2] + sh[3];
  float inv = 1.0f / s;
  ushort2 o; o.x = f2bf(e0 * inv); o.y = f2bf(e1 * inv);
  *(ushort2*)(out + row * 512 + threadIdx.x * 2) = o;
}

// ---------------- bf16 MFMA GEMM: C = A[M,K] @ Bt[Nc,K]^T ------------------
// m97 structure + 1-D grid with bijective XCD-chunked swizzle (m157):
// logical bid l = (hw%8)*q + hw/8 -> each XCD gets a contiguous logical span
// so blocks sharing an A-panel land on the SAME per-XCD L2.
// SPLIT: logical B is [q_w;k_w] (Nc=2048); x>=xh writes out2/bias2 (uniform).
template <int BIAS /*0 none,1 row,2 col*/, bool LEAKY, bool RESID, bool OUTF32, bool SPLIT>
__global__ __launch_bounds__(256) void gemm_bt(
    const unsigned short* __restrict__ A, size_t sA,
    const unsigned short* __restrict__ Bt, size_t sB,
    const float* __restrict__ bias, const float* __restrict__ bias2,
    const unsigned short* __restrict__ resid,
    void* __restrict__ out, void* __restrict__ out2,
    int M, int NcS, int K, int lgx, int lgy, int xh) {
  __shared__ unsigned short As[128 * 32];   // linear: row*32 + col, 64B rows
  __shared__ unsigned short Bs[128 * 32];
  // ---- XCD-chunked bijective swizzle (grid divisible by 8) ----
  const int qc = gridDim.x >> 3;
  const int dd = blockIdx.x;
  const int l = (dd & 7) * qc + (dd >> 3);
  const int x = l & ((1 << lgx) - 1);
  const int y = (l >> lgx) & ((1 << lgy) - 1);
  const int b = l >> (lgx + lgy);

  const unsigned short* Ab = A + sA * b;
  const unsigned short* Bb = Bt + sB * b;
  const int tM = y * 128, tN = x * 128;
  const int tid = threadIdx.x;
  const int wid = tid >> 6, lane = tid & 63;
  const int wr = wid >> 1, wc = wid & 1;
  const int l15 = lane & 15, l4 = lane >> 4;
  const int srow = wid * 16 + (lane >> 2);
  const int scol = (lane & 3) * 8;
  const unsigned short* gA = Ab + (size_t)(tM + srow) * K + scol;
  const unsigned short* gB = Bb + (size_t)(tN + srow) * K + scol;
  unsigned short* lA = As + wid * 512;      // wave-uniform LDS base (1KB/wave)
  unsigned short* lB = Bs + wid * 512;
  const size_t rowskip = (size_t)64 * K;

  f32x4 acc[4][4] = {};
  for (int k0 = 0; k0 < K; k0 += 32) {
    gload16(gA + k0, lA);
    gload16(gA + k0 + rowskip, lA + 2048);
    gload16(gB + k0, lB);
    gload16(gB + k0 + rowskip, lB + 2048);
    __syncthreads();                        // drains vmcnt before use
    bf16x8 af[4], bg[4];
#pragma unroll
    for (int i = 0; i < 4; i++) {
      af[i] = *(const bf16x8*)&As[(wr * 64 + i * 16 + l15) * 32 + l4 * 8];
      bg[i] = *(const bf16x8*)&Bs[(wc * 64 + i * 16 + l15) * 32 + l4 * 8];
    }
#pragma unroll
    for (int i = 0; i < 4; i++)
#pragma unroll
      for (int j = 0; j < 4; j++)
        acc[i][j] = __builtin_amdgcn_mfma_f32_16x16x32_bf16(af[i], bg[j], acc[i][j], 0, 0, 0);
    __syncthreads();
  }

  // block-uniform output select for the fused q|k dispatch
  const float* bia = bias;
  void* o = out;
  if (SPLIT && x >= xh) { bia = bias2; o = out2; }
  const size_t ob = (size_t)M * NcS * b;
#pragma unroll
  for (int i = 0; i < 4; i++)
#pragma unroll
    for (int j = 0; j < 4; j++) {
      const int cg = tN + wc * 64 + j * 16 + l15;
      const int rbase = tM + wr * 64 + i * 16 + l4 * 4;
#pragma unroll
      for (int r = 0; r < 4; r++) {
        const int rg = rbase + r;
        float v = acc[i][j][r];
        if (BIAS == 1) v += bia[rg];
        if (BIAS == 2) v += bia[cg];
        if (LEAKY) v = v > 0.0f ? v : 0.01f * v;
        const size_t idx = ob + (size_t)rg * NcS + cg;
        if (RESID) v += bf2f(resid[idx]);
        if (OUTF32) ((float*)o)[idx] = v;
        else        ((unsigned short*)o)[idx] = f2bf(v);
      }
    }
}

// ---------------------------------------------------------------------------
extern "C" void kernel_launch(void* const* d_in, const int* in_sizes, int n_in,
                              void* d_out, int out_size, void* d_ws, size_t ws_size,
                              hipStream_t stream) {
  const float* node_feats = (const float*)d_in[0];   // [16,1024,512]
  const float* adj        = (const float*)d_in[1];   // [16,1024,1024]
  const float* linear_w   = (const float*)d_in[2];   // [512,512]
  const float* linear_b   = (const float*)d_in[3];   // [512]
  const float* q_w        = (const float*)d_in[4];   // [1024,1024]
  const float* q_b        = (const float*)d_in[5];
  const float* k_w        = (const float*)d_in[6];
  const float* k_b        = (const float*)d_in[7];
  const float* v_w        = (const float*)d_in[8];
  const float* v_b        = (const float*)d_in[9];
  const float* n1w        = (const float*)d_in[10];  // [1024]
  const float* n1b        = (const float*)d_in[11];
  const float* n2w        = (const float*)d_in[12];  // [512]
  const float* n2b        = (const float*)d_in[13];
  const float* edge       = (const float*)d_in[14];  // [1024,1024]
  float* out = (float*)d_out;

  const int B = 16, N = 1024, C = 512;
  const size_t MiB = 1u << 20;
  char* w = (char*)d_ws;
  // lifetime-aliased workspace layout (total ~119.1 MiB)
  unsigned short* nf_bf   = (unsigned short*)(w);             // 16 MiB [dies after G1]
  unsigned short* Xt_bf   = (unsigned short*)(w + 16 * MiB);  // 16 MiB [dies after LN1]
  float*          att_raw = (float*)(w);                      // 16 MiB (reuses nf)
  unsigned short* WA_bf   = (unsigned short*)(w);             // 32 MiB (reuses nf+Xt, after softmax)
  unsigned short* Txln    = (unsigned short*)(w + 32 * MiB);  // 16 MiB
  unsigned short* q_bf    = (unsigned short*)(w + 48 * MiB);  // 16 MiB [dies after Gatt]
  unsigned short* X3_bf   = (unsigned short*)(w + 48 * MiB);  // 16 MiB (reuses q)
  unsigned short* k_bf    = (unsigned short*)(w + 64 * MiB);  // 16 MiB [dies after Gatt]
  unsigned short* att_bf  = (unsigned short*)(w + 64 * MiB);  //  8 MiB (reuses k)
  unsigned short* vt_bf   = (unsigned short*)(w + 80 * MiB);  // 16 MiB
  unsigned short* Tx2_bf  = (unsigned short*)(w + 96 * MiB);  // 16 MiB
  unsigned short* lw_bf   = (unsigned short*)(w + 112 * MiB); // 0.5 MiB
  unsigned short* qw_bf   = (unsigned short*)(w + 113 * MiB); // 2 MiB \ adjacent: one
  unsigned short* kw_bf   = (unsigned short*)(w + 115 * MiB); // 2 MiB / [2048,1024] matrix
  unsigned short* vw_bf   = (unsigned short*)(w + 117 * MiB); // 2 MiB
  float*          dis     = (float*)(w + 119 * MiB);          // 64 KiB

  // casts to bf16
  cast_kernel<<<(B * N * C / 4 + 255) / 256, 256, 0, stream>>>(node_feats, nf_bf, B * N * C / 4);
  cast_kernel<<<(C * C / 4 + 255) / 256, 256, 0, stream>>>(linear_w, lw_bf, C * C / 4);
  cast_kernel<<<(N * N / 4 + 255) / 256, 256, 0, stream>>>(q_w, qw_bf, N * N / 4);
  cast_kernel<<<(N * N / 4 + 255) / 256, 256, 0, stream>>>(k_w, kw_bf, N * N / 4);
  cast_kernel<<<(N * N / 4 + 255) / 256, 256, 0, stream>>>(v_w, vw_bf, N * N / 4);

  // degree normalization factors
  sigrow_kernel<<<B * N, 256, 0, stream>>>(adj, edge, dis);

  // G1: Xt[b,o,n] = leaky(lw @ nf^T + lb[o])   M=C, Nc=N, K=C  gx=8 gy=4
  gemm_bt<1, true, false, false, false><<<512, 256, 0, stream>>>(
      lw_bf, 0, nf_bf, (size_t)N * C, linear_b, nullptr, nullptr,
      Xt_bf, nullptr, C, N, C, 3, 2, 999);

  // LN1 over n (D=1024) -> Txln bf16
  ln_kernel<4, false><<<B * C, 256, 0, stream>>>(Xt_bf, n1w, n1b, Txln, N);

  // fused q|k: [b,x,g] = Txln @ [qw;kw]^T + [qb;kb]   M=C, Nc=2048, K=N
  // gx=16 gy=4; x<8 -> q, x>=8 -> k (out2/bias2 pre-shifted by -1024 cols)
  gemm_bt<2, false, false, false, true><<<1024, 256, 0, stream>>>(
      Txln, (size_t)C * N, qw_bf, 0, q_b, k_b - 1024, nullptr,
      q_bf, (void*)(k_bf - 1024), C, N, N, 4, 2, 8);

  // v^T: vt[b,g,x] = leaky(v_w @ Txln^T + v_b[g])   M=N, Nc=C, K=N  gx=4 gy=8
  gemm_bt<1, true, false, false, false><<<512, 256, 0, stream>>>(
      vw_bf, 0, Txln, (size_t)C * N, v_b, nullptr, nullptr,
      vt_bf, nullptr, N, C, N, 2, 3, 999);

  // att_raw[b,x,y] = q @ k^T   M=C, Nc=C, K=N   (f32 out)  gx=4 gy=4
  gemm_bt<0, false, false, true, false><<<256, 256, 0, stream>>>(
      q_bf, (size_t)C * N, k_bf, (size_t)C * N, nullptr, nullptr, nullptr,
      att_raw, nullptr, C, C, N, 2, 2, 999);

  // softmax(att_raw * 1/32) -> att_bf
  softmax_kernel<<<B * C, 256, 0, stream>>>(att_raw, att_bf);

  // W_A normalized bf16 (overwrites bytes [0,32MiB): nf/att_raw/Xt all dead)
  wa_kernel<<<B * N * N / 4 / 256, 256, 0, stream>>>(adj, edge, dis, WA_bf);

  // Tx2[b,x,h] = Txln + att @ v    M=C, Nc=N, K=C   (Bt = vt)  gx=8 gy=4
  gemm_bt<0, false, true, false, false><<<512, 256, 0, stream>>>(
      att_bf, (size_t)C * C, vt_bf, (size_t)N * C, nullptr, nullptr, Txln,
      Tx2_bf, nullptr, C, N, C, 3, 2, 999);

  // X3[b,n,o] = W_A @ X2          M=N, Nc=C, K=N   (Bt = Tx2)  gx=4 gy=8
  gemm_bt<0, false, false, false, false><<<512, 256, 0, stream>>>(
      WA_bf, (size_t)N * N, Tx2_bf, (size_t)C * N, nullptr, nullptr, nullptr,
      X3_bf, nullptr, N, C, N, 2, 3, 999);

  // final LN over o (D=512) -> f32 out
  ln_kernel<2, true><<<B * N, 256, 0, stream>>>(X3_bf, n2w, n2b, out, C);
}

// Round 4
// 253.863 us; speedup vs baseline: 1.3068x; 1.0529x over previous
//
#include <hip/hip_runtime.h>

// ---------------------------------------------------------------------------
// Channel_Transformer_WGCNLayer  (B=16, N=1024, C=512)  -- bf16 MFMA pipeline
// All GEMMs: C[M,Nc] = A[M,K] @ Bt[Nc,K]^T  (K contiguous on both operands)
// GEMM: 128x128 tile, BK=32, global_load_lds w=16, XCD-chunked swizzle,
//       2-phase double-buffered LDS (stage t+1 before compute t; one barrier
//       per K-step so the vmcnt drain hides behind ds_read+MFMA).
// ---------------------------------------------------------------------------

typedef __bf16 bf16x8 __attribute__((ext_vector_type(8)));
typedef float  f32x4  __attribute__((ext_vector_type(4)));

#define DEV __device__ __forceinline__

DEV float bf2f(unsigned short u) {
  union { unsigned i; float f; } x; x.i = ((unsigned)u) << 16; return x.f;
}
DEV unsigned short f2bf(float f) {           // round-to-nearest-even
  unsigned u = __float_as_uint(f);
  u += 0x7fffu + ((u >> 16) & 1u);
  return (unsigned short)(u >> 16);
}
DEV float sigmoidf_(float x) { return 1.0f / (1.0f + __expf(-x)); }

DEV float wave_sum(float v) {
#pragma unroll
  for (int o = 32; o > 0; o >>= 1) v += __shfl_xor(v, o, 64);
  return v;
}
DEV float wave_max(float v) {
#pragma unroll
  for (int o = 32; o > 0; o >>= 1) v = fmaxf(v, __shfl_xor(v, o, 64));
  return v;
}

// async global->LDS, 16B per lane; lds dest is wave-uniform (HW adds lane*16)
DEV void gload16(const unsigned short* g, unsigned short* l) {
  __builtin_amdgcn_global_load_lds(
      (const __attribute__((address_space(1))) unsigned int*)g,
      (__attribute__((address_space(3))) unsigned int*)l, 16, 0, 0);
}

// ---------------------------- f32 -> bf16 cast -----------------------------
__global__ __launch_bounds__(256) void cast_kernel(const float* __restrict__ in,
                                                   unsigned short* __restrict__ out,
                                                   int n4) {
  int g = blockIdx.x * 256 + threadIdx.x;
  if (g >= n4) return;
  float4 v = *(const float4*)(in + (size_t)g * 4);
  ushort4 o;
  o.x = f2bf(v.x); o.y = f2bf(v.y); o.z = f2bf(v.z); o.w = f2bf(v.w);
  *(ushort4*)(out + (size_t)g * 4) = o;
}

// ------------------- degree: d_is[b,n] = rsqrt(sum_m adj*sig) --------------
__global__ __launch_bounds__(256) void sigrow_kernel(const float* __restrict__ adj,
                                                     const float* __restrict__ edge,
                                                     float* __restrict__ dis) {
  __shared__ float sh[4];
  size_t row = blockIdx.x;                 // b*1024 + n
  int n = (int)(row & 1023);
  const float* ar = adj + row * 1024;
  const float* er = edge + (size_t)n * 1024;
  int c = threadIdx.x * 4;
  float4 a4 = *(const float4*)(ar + c);
  float4 e4 = *(const float4*)(er + c);
  float s = a4.x * sigmoidf_(e4.x) + a4.y * sigmoidf_(e4.y) +
            a4.z * sigmoidf_(e4.z) + a4.w * sigmoidf_(e4.w);
  s = wave_sum(s);
  if ((threadIdx.x & 63) == 0) sh[threadIdx.x >> 6] = s;
  __syncthreads();
  if (threadIdx.x == 0) {
    float t = sh[0] + sh[1] + sh[2] + sh[3];
    dis[row] = t > 0.0f ? rsqrtf(t) : 0.0f;
  }
}

// -------------- W_A_norm[b,n,m] = d[n]*adj*sig(edge)*d[m] -> bf16 ----------
__global__ __launch_bounds__(256) void wa_kernel(const float* __restrict__ adj,
                                                 const float* __restrict__ edge,
                                                 const float* __restrict__ dis,
                                                 unsigned short* __restrict__ wa) {
  size_t g = (size_t)blockIdx.x * 256 + threadIdx.x;   // group of 4 along m
  int m = (int)(g & 255) * 4;
  size_t rest = g >> 8;                                // b*1024 + n
  int n = (int)(rest & 1023);
  int b = (int)(rest >> 10);
  float4 a4 = *(const float4*)(adj + rest * 1024 + m);
  float4 e4 = *(const float4*)(edge + (size_t)n * 1024 + m);
  float dn = dis[rest];
  float4 dm = *(const float4*)(dis + (size_t)b * 1024 + m);
  ushort4 o;
  o.x = f2bf(dn * a4.x * sigmoidf_(e4.x) * dm.x);
  o.y = f2bf(dn * a4.y * sigmoidf_(e4.y) * dm.y);
  o.z = f2bf(dn * a4.z * sigmoidf_(e4.z) * dm.z);
  o.w = f2bf(dn * a4.w * sigmoidf_(e4.w) * dm.w);
  *(ushort4*)(wa + g * 4) = o;
}

// --------------------------- LayerNorm over rows ---------------------------
template <int VPT, bool OUTF32>
__global__ __launch_bounds__(256) void ln_kernel(const unsigned short* __restrict__ in,
                                                 const float* __restrict__ gw,
                                                 const float* __restrict__ gb,
                                                 void* __restrict__ out, int D) {
  __shared__ float sh[8];
  size_t row = blockIdx.x;
  const unsigned short* x = in + row * (size_t)D;
  int base = threadIdx.x * VPT;
  float v[VPT];
  if (VPT == 4) {
    ushort4 u = *(const ushort4*)(x + base);
    v[0] = bf2f(u.x); v[1] = bf2f(u.y); v[2] = bf2f(u.z); v[3] = bf2f(u.w);
  } else {
    ushort2 u = *(const ushort2*)(x + base);
    v[0] = bf2f(u.x); v[1] = bf2f(u.y);
  }
  float s = 0.f, sq = 0.f;
#pragma unroll
  for (int i = 0; i < VPT; i++) { s += v[i]; sq += v[i] * v[i]; }
  s = wave_sum(s); sq = wave_sum(sq);
  if ((threadIdx.x & 63) == 0) { sh[threadIdx.x >> 6] = s; sh[4 + (threadIdx.x >> 6)] = sq; }
  __syncthreads();
  s = sh[0] + sh[1] + sh[2] + sh[3];
  sq = sh[4] + sh[5] + sh[6] + sh[7];
  float mean = s / D;
  float var = sq / D - mean * mean;
  float rs = rsqrtf(fmaxf(var, 0.0f) + 1e-5f);
#pragma unroll
  for (int i = 0; i < VPT; i++) {
    float y = (v[i] - mean) * rs * gw[base + i] + gb[base + i];
    if (OUTF32) ((float*)out)[row * D + base + i] = y;
    else        ((unsigned short*)out)[row * D + base + i] = f2bf(y);
  }
}

// ------------------------- softmax over rows of 512 ------------------------
__global__ __launch_bounds__(256) void softmax_kernel(const float* __restrict__ in,
                                                      unsigned short* __restrict__ out) {
  __shared__ float sh[4];
  size_t row = blockIdx.x;
  const float* x = in + row * 512;
  float2 u = *(const float2*)(x + threadIdx.x * 2);
  float a = u.x * 0.03125f, b = u.y * 0.03125f;   // channel_scale = 1024^-0.5
  float m = wave_max(fmaxf(a, b));
  int wid = threadIdx.x >> 6;
  if ((threadIdx.x & 63) == 0) sh[wid] = m;
  __syncthreads();
  m = fmaxf(fmaxf(sh[0], sh[1]), fmaxf(sh[2], sh[3]));
  __syncthreads();
  float e0 = __expf(a - m), e1 = __expf(b - m);
  float s = wave_sum(e0 + e1);
  if ((threadIdx.x & 63) == 0) sh[wid] = s;
  __syncthreads();
  s = sh[0] + sh[1] + sh[2] + sh[3];
  float inv = 1.0f / s;
  ushort2 o; o.x = f2bf(e0 * inv); o.y = f2bf(e1 * inv);
  *(ushort2*)(out + row * 512 + threadIdx.x * 2) = o;
}

// ---------------- bf16 MFMA GEMM: C = A[M,K] @ Bt[Nc,K]^T ------------------
// 2-phase double-buffered: stage tile t+1 while computing tile t. One
// __syncthreads per K-step; its vmcnt(0)+lgkmcnt(0) drain covers (a) next
// buffer's global_load_lds completion and (b) all ds_reads of the buffer
// about to be overwritten. t-loop unrolled x2 for static buffer indices.
template <int BIAS /*0 none,1 row,2 col*/, bool LEAKY, bool RESID, bool OUTF32, bool SPLIT>
__global__ __launch_bounds__(256) void gemm_bt(
    const unsigned short* __restrict__ A, size_t sA,
    const unsigned short* __restrict__ Bt, size_t sB,
    const float* __restrict__ bias, const float* __restrict__ bias2,
    const unsigned short* __restrict__ resid,
    void* __restrict__ out, void* __restrict__ out2,
    int M, int NcS, int K, int lgx, int lgy, int xh) {
  __shared__ unsigned short As[2][128 * 32];   // linear: row*32 + col
  __shared__ unsigned short Bs[2][128 * 32];
  // ---- XCD-chunked bijective swizzle (grid divisible by 8) ----
  const int qc = gridDim.x >> 3;
  const int dd = blockIdx.x;
  const int l = (dd & 7) * qc + (dd >> 3);
  const int x = l & ((1 << lgx) - 1);
  const int y = (l >> lgx) & ((1 << lgy) - 1);
  const int b = l >> (lgx + lgy);

  const unsigned short* Ab = A + sA * b;
  const unsigned short* Bb = Bt + sB * b;
  const int tM = y * 128, tN = x * 128;
  const int tid = threadIdx.x;
  const int wid = tid >> 6, lane = tid & 63;
  const int wr = wid >> 1, wc = wid & 1;
  const int l15 = lane & 15, l4 = lane >> 4;
  const int srow = wid * 16 + (lane >> 2);
  const int scol = (lane & 3) * 8;
  const unsigned short* gA = Ab + (size_t)(tM + srow) * K + scol;
  const unsigned short* gB = Bb + (size_t)(tN + srow) * K + scol;
  const size_t rowskip = (size_t)64 * K;
  const int ldsoff = wid * 512;                // wave-uniform LDS base

  auto STAGE = [&](unsigned short* bufA, unsigned short* bufB, int k0) {
    gload16(gA + k0, bufA + ldsoff);
    gload16(gA + k0 + rowskip, bufA + ldsoff + 2048);
    gload16(gB + k0, bufB + ldsoff);
    gload16(gB + k0 + rowskip, bufB + ldsoff + 2048);
  };

  f32x4 acc[4][4] = {};
  auto COMPUTE = [&](const unsigned short* bA, const unsigned short* bB) {
    bf16x8 af[4], bg[4];
#pragma unroll
    for (int i = 0; i < 4; i++) {
      af[i] = *(const bf16x8*)&bA[(wr * 64 + i * 16 + l15) * 32 + l4 * 8];
      bg[i] = *(const bf16x8*)&bB[(wc * 64 + i * 16 + l15) * 32 + l4 * 8];
    }
#pragma unroll
    for (int i = 0; i < 4; i++)
#pragma unroll
      for (int j = 0; j < 4; j++)
        acc[i][j] = __builtin_amdgcn_mfma_f32_16x16x32_bf16(af[i], bg[j], acc[i][j], 0, 0, 0);
  };

  const int nt = K >> 5;                       // 16 or 32: always even
  STAGE(As[0], Bs[0], 0);                      // prologue: tile 0 -> buf0
  for (int t = 0; t < nt; t += 2) {
    __syncthreads();                           // buf0 ready; buf1 reads done
    STAGE(As[1], Bs[1], (t + 1) << 5);         // prefetch t+1 -> buf1
    COMPUTE(As[0], Bs[0]);                     // compute tile t
    __syncthreads();                           // buf1 ready; buf0 reads done
    if (t + 2 < nt) STAGE(As[0], Bs[0], (t + 2) << 5);
    COMPUTE(As[1], Bs[1]);                     // compute tile t+1
  }

  // block-uniform output select for the fused q|k dispatch
  const float* bia = bias;
  void* o = out;
  if (SPLIT && x >= xh) { bia = bias2; o = out2; }
  const size_t ob = (size_t)M * NcS * b;
#pragma unroll
  for (int i = 0; i < 4; i++)
#pragma unroll
    for (int j = 0; j < 4; j++) {
      const int cg = tN + wc * 64 + j * 16 + l15;
      const int rbase = tM + wr * 64 + i * 16 + l4 * 4;
#pragma unroll
      for (int r = 0; r < 4; r++) {
        const int rg = rbase + r;
        float v = acc[i][j][r];
        if (BIAS == 1) v += bia[rg];
        if (BIAS == 2) v += bia[cg];
        if (LEAKY) v = v > 0.0f ? v : 0.01f * v;
        const size_t idx = ob + (size_t)rg * NcS + cg;
        if (RESID) v += bf2f(resid[idx]);
        if (OUTF32) ((float*)o)[idx] = v;
        else        ((unsigned short*)o)[idx] = f2bf(v);
      }
    }
}

// ---------------------------------------------------------------------------
extern "C" void kernel_launch(void* const* d_in, const int* in_sizes, int n_in,
                              void* d_out, int out_size, void* d_ws, size_t ws_size,
                              hipStream_t stream) {
  const float* node_feats = (const float*)d_in[0];   // [16,1024,512]
  const float* adj        = (const float*)d_in[1];   // [16,1024,1024]
  const float* linear_w   = (const float*)d_in[2];   // [512,512]
  const float* linear_b   = (const float*)d_in[3];   // [512]
  const float* q_w        = (const float*)d_in[4];   // [1024,1024]
  const float* q_b        = (const float*)d_in[5];
  const float* k_w        = (const float*)d_in[6];
  const float* k_b        = (const float*)d_in[7];
  const float* v_w        = (const float*)d_in[8];
  const float* v_b        = (const float*)d_in[9];
  const float* n1w        = (const float*)d_in[10];  // [1024]
  const float* n1b        = (const float*)d_in[11];
  const float* n2w        = (const float*)d_in[12];  // [512]
  const float* n2b        = (const float*)d_in[13];
  const float* edge       = (const float*)d_in[14];  // [1024,1024]
  float* out = (float*)d_out;

  const int B = 16, N = 1024, C = 512;
  const size_t MiB = 1u << 20;
  char* w = (char*)d_ws;
  // lifetime-aliased workspace layout (total ~119.1 MiB)
  unsigned short* nf_bf   = (unsigned short*)(w);             // 16 MiB [dies after G1]
  unsigned short* Xt_bf   = (unsigned short*)(w + 16 * MiB);  // 16 MiB [dies after LN1]
  float*          att_raw = (float*)(w);                      // 16 MiB (reuses nf)
  unsigned short* WA_bf   = (unsigned short*)(w);             // 32 MiB (reuses nf+Xt, after softmax)
  unsigned short* Txln    = (unsigned short*)(w + 32 * MiB);  // 16 MiB
  unsigned short* q_bf    = (unsigned short*)(w + 48 * MiB);  // 16 MiB [dies after Gatt]
  unsigned short* X3_bf   = (unsigned short*)(w + 48 * MiB);  // 16 MiB (reuses q)
  unsigned short* k_bf    = (unsigned short*)(w + 64 * MiB);  // 16 MiB [dies after Gatt]
  unsigned short* att_bf  = (unsigned short*)(w + 64 * MiB);  //  8 MiB (reuses k)
  unsigned short* vt_bf   = (unsigned short*)(w + 80 * MiB);  // 16 MiB
  unsigned short* Tx2_bf  = (unsigned short*)(w + 96 * MiB);  // 16 MiB
  unsigned short* lw_bf   = (unsigned short*)(w + 112 * MiB); // 0.5 MiB
  unsigned short* qw_bf   = (unsigned short*)(w + 113 * MiB); // 2 MiB \ adjacent: one
  unsigned short* kw_bf   = (unsigned short*)(w + 115 * MiB); // 2 MiB / [2048,1024] matrix
  unsigned short* vw_bf   = (unsigned short*)(w + 117 * MiB); // 2 MiB
  float*          dis     = (float*)(w + 119 * MiB);          // 64 KiB

  // casts to bf16
  cast_kernel<<<(B * N * C / 4 + 255) / 256, 256, 0, stream>>>(node_feats, nf_bf, B * N * C / 4);
  cast_kernel<<<(C * C / 4 + 255) / 256, 256, 0, stream>>>(linear_w, lw_bf, C * C / 4);
  cast_kernel<<<(N * N / 4 + 255) / 256, 256, 0, stream>>>(q_w, qw_bf, N * N / 4);
  cast_kernel<<<(N * N / 4 + 255) / 256, 256, 0, stream>>>(k_w, kw_bf, N * N / 4);
  cast_kernel<<<(N * N / 4 + 255) / 256, 256, 0, stream>>>(v_w, vw_bf, N * N / 4);

  // degree normalization factors
  sigrow_kernel<<<B * N, 256, 0, stream>>>(adj, edge, dis);

  // G1: Xt[b,o,n] = leaky(lw @ nf^T + lb[o])   M=C, Nc=N, K=C  gx=8 gy=4
  gemm_bt<1, true, false, false, false><<<512, 256, 0, stream>>>(
      lw_bf, 0, nf_bf, (size_t)N * C, linear_b, nullptr, nullptr,
      Xt_bf, nullptr, C, N, C, 3, 2, 999);

  // LN1 over n (D=1024) -> Txln bf16
  ln_kernel<4, false><<<B * C, 256, 0, stream>>>(Xt_bf, n1w, n1b, Txln, N);

  // fused q|k: [b,x,g] = Txln @ [qw;kw]^T + [qb;kb]   M=C, Nc=2048, K=N
  // gx=16 gy=4; x<8 -> q, x>=8 -> k (out2/bias2 pre-shifted by -1024 cols)
  gemm_bt<2, false, false, false, true><<<1024, 256, 0, stream>>>(
      Txln, (size_t)C * N, qw_bf, 0, q_b, k_b - 1024, nullptr,
      q_bf, (void*)(k_bf - 1024), C, N, N, 4, 2, 8);

  // v^T: vt[b,g,x] = leaky(v_w @ Txln^T + v_b[g])   M=N, Nc=C, K=N  gx=4 gy=8
  gemm_bt<1, true, false, false, false><<<512, 256, 0, stream>>>(
      vw_bf, 0, Txln, (size_t)C * N, v_b, nullptr, nullptr,
      vt_bf, nullptr, N, C, N, 2, 3, 999);

  // att_raw[b,x,y] = q @ k^T   M=C, Nc=C, K=N   (f32 out)  gx=4 gy=4
  gemm_bt<0, false, false, true, false><<<256, 256, 0, stream>>>(
      q_bf, (size_t)C * N, k_bf, (size_t)C * N, nullptr, nullptr, nullptr,
      att_raw, nullptr, C, C, N, 2, 2, 999);

  // softmax(att_raw * 1/32) -> att_bf
  softmax_kernel<<<B * C, 256, 0, stream>>>(att_raw, att_bf);

  // W_A normalized bf16 (overwrites bytes [0,32MiB): nf/att_raw/Xt all dead)
  wa_kernel<<<B * N * N / 4 / 256, 256, 0, stream>>>(adj, edge, dis, WA_bf);

  // Tx2[b,x,h] = Txln + att @ v    M=C, Nc=N, K=C   (Bt = vt)  gx=8 gy=4
  gemm_bt<0, false, true, false, false><<<512, 256, 0, stream>>>(
      att_bf, (size_t)C * C, vt_bf, (size_t)N * C, nullptr, nullptr, Txln,
      Tx2_bf, nullptr, C, N, C, 3, 2, 999);

  // X3[b,n,o] = W_A @ X2          M=N, Nc=C, K=N   (Bt = Tx2)  gx=4 gy=8
  gemm_bt<0, false, false, false, false><<<512, 256, 0, stream>>>(
      WA_bf, (size_t)N * N, Tx2_bf, (size_t)C * N, nullptr, nullptr, nullptr,
      X3_bf, nullptr, N, C, N, 2, 3, 999);

  // final LN over o (D=512) -> f32 out
  ln_kernel<2, true><<<B * N, 256, 0, stream>>>(X3_bf, n2w, n2b, out, C);
}

// Round 5
// 249.829 us; speedup vs baseline: 1.3279x; 1.0161x over previous
//
#include <hip/hip_runtime.h>

// ---------------------------------------------------------------------------
// Channel_Transformer_WGCNLayer  (B=16, N=1024, C=512)  -- bf16 MFMA pipeline
// All GEMMs: C[M,Nc] = A[M,K] @ Bt[Nc,K]^T  (K contiguous on both operands)
// GEMM: 128x128 tile, BK=32, global_load_lds w=16, XCD-chunked swizzle,
//       double-buffered LDS with COUNTED vmcnt(4) + raw s_barrier (T4):
//       prefetch loads stay in flight across the barrier; only the previous
//       tile's 4 loads are waited. No vmcnt(0) drain in the main loop.
// ---------------------------------------------------------------------------

typedef __bf16 bf16x8 __attribute__((ext_vector_type(8)));
typedef float  f32x4  __attribute__((ext_vector_type(4)));

#define DEV __device__ __forceinline__

DEV float bf2f(unsigned short u) {
  union { unsigned i; float f; } x; x.i = ((unsigned)u) << 16; return x.f;
}
DEV unsigned short f2bf(float f) {           // round-to-nearest-even
  unsigned u = __float_as_uint(f);
  u += 0x7fffu + ((u >> 16) & 1u);
  return (unsigned short)(u >> 16);
}
DEV float sigmoidf_(float x) { return 1.0f / (1.0f + __expf(-x)); }

DEV float wave_sum(float v) {
#pragma unroll
  for (int o = 32; o > 0; o >>= 1) v += __shfl_xor(v, o, 64);
  return v;
}
DEV float wave_max(float v) {
#pragma unroll
  for (int o = 32; o > 0; o >>= 1) v = fmaxf(v, __shfl_xor(v, o, 64));
  return v;
}

// async global->LDS, 16B per lane; lds dest is wave-uniform (HW adds lane*16)
DEV void gload16(const unsigned short* g, unsigned short* l) {
  __builtin_amdgcn_global_load_lds(
      (const __attribute__((address_space(1))) unsigned int*)g,
      (__attribute__((address_space(3))) unsigned int*)l, 16, 0, 0);
}

// raw barrier / counted waits (no implicit vmcnt(0) drain, unlike __syncthreads)
#define BAR()        asm volatile("s_barrier" ::: "memory")
#define WAIT_VM(n)   asm volatile("s_waitcnt vmcnt(" #n ")" ::: "memory")

// ---------------------------- f32 -> bf16 cast -----------------------------
__global__ __launch_bounds__(256) void cast_kernel(const float* __restrict__ in,
                                                   unsigned short* __restrict__ out,
                                                   int n4) {
  int g = blockIdx.x * 256 + threadIdx.x;
  if (g >= n4) return;
  float4 v = *(const float4*)(in + (size_t)g * 4);
  ushort4 o;
  o.x = f2bf(v.x); o.y = f2bf(v.y); o.z = f2bf(v.z); o.w = f2bf(v.w);
  *(ushort4*)(out + (size_t)g * 4) = o;
}

// ------------------- degree: d_is[b,n] = rsqrt(sum_m adj*sig) --------------
__global__ __launch_bounds__(256) void sigrow_kernel(const float* __restrict__ adj,
                                                     const float* __restrict__ edge,
                                                     float* __restrict__ dis) {
  __shared__ float sh[4];
  size_t row = blockIdx.x;                 // b*1024 + n
  int n = (int)(row & 1023);
  const float* ar = adj + row * 1024;
  const float* er = edge + (size_t)n * 1024;
  int c = threadIdx.x * 4;
  float4 a4 = *(const float4*)(ar + c);
  float4 e4 = *(const float4*)(er + c);
  float s = a4.x * sigmoidf_(e4.x) + a4.y * sigmoidf_(e4.y) +
            a4.z * sigmoidf_(e4.z) + a4.w * sigmoidf_(e4.w);
  s = wave_sum(s);
  if ((threadIdx.x & 63) == 0) sh[threadIdx.x >> 6] = s;
  __syncthreads();
  if (threadIdx.x == 0) {
    float t = sh[0] + sh[1] + sh[2] + sh[3];
    dis[row] = t > 0.0f ? rsqrtf(t) : 0.0f;
  }
}

// -------------- W_A_norm[b,n,m] = d[n]*adj*sig(edge)*d[m] -> bf16 ----------
__global__ __launch_bounds__(256) void wa_kernel(const float* __restrict__ adj,
                                                 const float* __restrict__ edge,
                                                 const float* __restrict__ dis,
                                                 unsigned short* __restrict__ wa) {
  size_t g = (size_t)blockIdx.x * 256 + threadIdx.x;   // group of 4 along m
  int m = (int)(g & 255) * 4;
  size_t rest = g >> 8;                                // b*1024 + n
  int n = (int)(rest & 1023);
  int b = (int)(rest >> 10);
  float4 a4 = *(const float4*)(adj + rest * 1024 + m);
  float4 e4 = *(const float4*)(edge + (size_t)n * 1024 + m);
  float dn = dis[rest];
  float4 dm = *(const float4*)(dis + (size_t)b * 1024 + m);
  ushort4 o;
  o.x = f2bf(dn * a4.x * sigmoidf_(e4.x) * dm.x);
  o.y = f2bf(dn * a4.y * sigmoidf_(e4.y) * dm.y);
  o.z = f2bf(dn * a4.z * sigmoidf_(e4.z) * dm.z);
  o.w = f2bf(dn * a4.w * sigmoidf_(e4.w) * dm.w);
  *(ushort4*)(wa + g * 4) = o;
}

// --------------------------- LayerNorm over rows ---------------------------
template <int VPT, bool OUTF32>
__global__ __launch_bounds__(256) void ln_kernel(const unsigned short* __restrict__ in,
                                                 const float* __restrict__ gw,
                                                 const float* __restrict__ gb,
                                                 void* __restrict__ out, int D) {
  __shared__ float sh[8];
  size_t row = blockIdx.x;
  const unsigned short* x = in + row * (size_t)D;
  int base = threadIdx.x * VPT;
  float v[VPT];
  if (VPT == 4) {
    ushort4 u = *(const ushort4*)(x + base);
    v[0] = bf2f(u.x); v[1] = bf2f(u.y); v[2] = bf2f(u.z); v[3] = bf2f(u.w);
  } else {
    ushort2 u = *(const ushort2*)(x + base);
    v[0] = bf2f(u.x); v[1] = bf2f(u.y);
  }
  float s = 0.f, sq = 0.f;
#pragma unroll
  for (int i = 0; i < VPT; i++) { s += v[i]; sq += v[i] * v[i]; }
  s = wave_sum(s); sq = wave_sum(sq);
  if ((threadIdx.x & 63) == 0) { sh[threadIdx.x >> 6] = s; sh[4 + (threadIdx.x >> 6)] = sq; }
  __syncthreads();
  s = sh[0] + sh[1] + sh[2] + sh[3];
  sq = sh[4] + sh[5] + sh[6] + sh[7];
  float mean = s / D;
  float var = sq / D - mean * mean;
  float rs = rsqrtf(fmaxf(var, 0.0f) + 1e-5f);
#pragma unroll
  for (int i = 0; i < VPT; i++) {
    float y = (v[i] - mean) * rs * gw[base + i] + gb[base + i];
    if (OUTF32) ((float*)out)[row * D + base + i] = y;
    else        ((unsigned short*)out)[row * D + base + i] = f2bf(y);
  }
}

// ------------------------- softmax over rows of 512 ------------------------
__global__ __launch_bounds__(256) void softmax_kernel(const float* __restrict__ in,
                                                      unsigned short* __restrict__ out) {
  __shared__ float sh[4];
  size_t row = blockIdx.x;
  const float* x = in + row * 512;
  float2 u = *(const float2*)(x + threadIdx.x * 2);
  float a = u.x * 0.03125f, b = u.y * 0.03125f;   // channel_scale = 1024^-0.5
  float m = wave_max(fmaxf(a, b));
  int wid = threadIdx.x >> 6;
  if ((threadIdx.x & 63) == 0) sh[wid] = m;
  __syncthreads();
  m = fmaxf(fmaxf(sh[0], sh[1]), fmaxf(sh[2], sh[3]));
  __syncthreads();
  float e0 = __expf(a - m), e1 = __expf(b - m);
  float s = wave_sum(e0 + e1);
  if ((threadIdx.x & 63) == 0) sh[wid] = s;
  __syncthreads();
  s = sh[0] + sh[1] + sh[2] + sh[3];
  float inv = 1.0f / s;
  ushort2 o; o.x = f2bf(e0 * inv); o.y = f2bf(e1 * inv);
  *(ushort2*)(out + row * 512 + threadIdx.x * 2) = o;
}

// ---------------- bf16 MFMA GEMM: C = A[M,K] @ Bt[Nc,K]^T ------------------
// Pipelined double-buffer with counted vmcnt:
//   iter half for buf X: STAGE(other, t+1) -> vmcnt(4) [X's loads done]
//   -> s_barrier [all waves' X loads done] -> ds_read+MFMA on X
//   -> s_barrier [all reads of X done; X may be overwritten next half].
// ds_reads are drained by compiler lgkmcnt before MFMA, so the 2nd barrier
// needs no explicit waitcnt. Only the last tile waits vmcnt(0).
template <int BIAS /*0 none,1 row,2 col*/, bool LEAKY, bool RESID, bool OUTF32, bool SPLIT>
__global__ __launch_bounds__(256) void gemm_bt(
    const unsigned short* __restrict__ A, size_t sA,
    const unsigned short* __restrict__ Bt, size_t sB,
    const float* __restrict__ bias, const float* __restrict__ bias2,
    const unsigned short* __restrict__ resid,
    void* __restrict__ out, void* __restrict__ out2,
    int M, int NcS, int K, int lgx, int lgy, int xh) {
  __shared__ unsigned short As[2][128 * 32];   // linear: row*32 + col
  __shared__ unsigned short Bs[2][128 * 32];
  // ---- XCD-chunked bijective swizzle (grid divisible by 8) ----
  const int qc = gridDim.x >> 3;
  const int dd = blockIdx.x;
  const int l = (dd & 7) * qc + (dd >> 3);
  const int x = l & ((1 << lgx) - 1);
  const int y = (l >> lgx) & ((1 << lgy) - 1);
  const int b = l >> (lgx + lgy);

  const unsigned short* Ab = A + sA * b;
  const unsigned short* Bb = Bt + sB * b;
  const int tM = y * 128, tN = x * 128;
  const int tid = threadIdx.x;
  const int wid = tid >> 6, lane = tid & 63;
  const int wr = wid >> 1, wc = wid & 1;
  const int l15 = lane & 15, l4 = lane >> 4;
  const int srow = wid * 16 + (lane >> 2);
  const int scol = (lane & 3) * 8;
  const unsigned short* gA = Ab + (size_t)(tM + srow) * K + scol;
  const unsigned short* gB = Bb + (size_t)(tN + srow) * K + scol;
  const size_t rowskip = (size_t)64 * K;
  const int ldsoff = wid * 512;                // wave-uniform LDS base

  auto STAGE = [&](unsigned short* bufA, unsigned short* bufB, int k0) {
    gload16(gA + k0, bufA + ldsoff);
    gload16(gA + k0 + rowskip, bufA + ldsoff + 2048);
    gload16(gB + k0, bufB + ldsoff);
    gload16(gB + k0 + rowskip, bufB + ldsoff + 2048);
  };

  f32x4 acc[4][4] = {};
  auto COMPUTE = [&](const unsigned short* bA, const unsigned short* bB) {
    bf16x8 af[4], bg[4];
#pragma unroll
    for (int i = 0; i < 4; i++) {
      af[i] = *(const bf16x8*)&bA[(wr * 64 + i * 16 + l15) * 32 + l4 * 8];
      bg[i] = *(const bf16x8*)&bB[(wc * 64 + i * 16 + l15) * 32 + l4 * 8];
    }
#pragma unroll
    for (int i = 0; i < 4; i++)
#pragma unroll
      for (int j = 0; j < 4; j++)
        acc[i][j] = __builtin_amdgcn_mfma_f32_16x16x32_bf16(af[i], bg[j], acc[i][j], 0, 0, 0);
  };

  const int nt = K >> 5;                       // 16 or 32: always even
  STAGE(As[0], Bs[0], 0);                      // prologue: tile 0 -> buf0
  for (int t = 0; t < nt; t += 2) {
    // ---- half A: compute buf0 (tile t), prefetch buf1 (tile t+1) ----
    STAGE(As[1], Bs[1], (t + 1) << 5);         // 8 loads now in flight
    WAIT_VM(4);                                // oldest 4 (buf0) landed
    BAR();                                     // ... for ALL waves
    COMPUTE(As[0], Bs[0]);
    BAR();                                     // all reads of buf0 done
    // ---- half B: compute buf1 (tile t+1), prefetch buf0 (tile t+2) ----
    if (t + 2 < nt) {
      STAGE(As[0], Bs[0], (t + 2) << 5);
      WAIT_VM(4);
    } else {
      WAIT_VM(0);                              // epilogue: drain buf1's loads
    }
    BAR();
    COMPUTE(As[1], Bs[1]);
    BAR();                                     // buf1 reads done (next overwrite)
  }

  // block-uniform output select for the fused q|k dispatch
  const float* bia = bias;
  void* o = out;
  if (SPLIT && x >= xh) { bia = bias2; o = out2; }
  const size_t ob = (size_t)M * NcS * b;
#pragma unroll
  for (int i = 0; i < 4; i++)
#pragma unroll
    for (int j = 0; j < 4; j++) {
      const int cg = tN + wc * 64 + j * 16 + l15;
      const int rbase = tM + wr * 64 + i * 16 + l4 * 4;
#pragma unroll
      for (int r = 0; r < 4; r++) {
        const int rg = rbase + r;
        float v = acc[i][j][r];
        if (BIAS == 1) v += bia[rg];
        if (BIAS == 2) v += bia[cg];
        if (LEAKY) v = v > 0.0f ? v : 0.01f * v;
        const size_t idx = ob + (size_t)rg * NcS + cg;
        if (RESID) v += bf2f(resid[idx]);
        if (OUTF32) ((float*)o)[idx] = v;
        else        ((unsigned short*)o)[idx] = f2bf(v);
      }
    }
}

// ---------------------------------------------------------------------------
extern "C" void kernel_launch(void* const* d_in, const int* in_sizes, int n_in,
                              void* d_out, int out_size, void* d_ws, size_t ws_size,
                              hipStream_t stream) {
  const float* node_feats = (const float*)d_in[0];   // [16,1024,512]
  const float* adj        = (const float*)d_in[1];   // [16,1024,1024]
  const float* linear_w   = (const float*)d_in[2];   // [512,512]
  const float* linear_b   = (const float*)d_in[3];   // [512]
  const float* q_w        = (const float*)d_in[4];   // [1024,1024]
  const float* q_b        = (const float*)d_in[5];
  const float* k_w        = (const float*)d_in[6];
  const float* k_b        = (const float*)d_in[7];
  const float* v_w        = (const float*)d_in[8];
  const float* v_b        = (const float*)d_in[9];
  const float* n1w        = (const float*)d_in[10];  // [1024]
  const float* n1b        = (const float*)d_in[11];
  const float* n2w        = (const float*)d_in[12];  // [512]
  const float* n2b        = (const float*)d_in[13];
  const float* edge       = (const float*)d_in[14];  // [1024,1024]
  float* out = (float*)d_out;

  const int B = 16, N = 1024, C = 512;
  const size_t MiB = 1u << 20;
  char* w = (char*)d_ws;
  // lifetime-aliased workspace layout (total ~119.1 MiB)
  unsigned short* nf_bf   = (unsigned short*)(w);             // 16 MiB [dies after G1]
  unsigned short* Xt_bf   = (unsigned short*)(w + 16 * MiB);  // 16 MiB [dies after LN1]
  float*          att_raw = (float*)(w);                      // 16 MiB (reuses nf)
  unsigned short* WA_bf   = (unsigned short*)(w);             // 32 MiB (reuses nf+Xt, after softmax)
  unsigned short* Txln    = (unsigned short*)(w + 32 * MiB);  // 16 MiB
  unsigned short* q_bf    = (unsigned short*)(w + 48 * MiB);  // 16 MiB [dies after Gatt]
  unsigned short* X3_bf   = (unsigned short*)(w + 48 * MiB);  // 16 MiB (reuses q)
  unsigned short* k_bf    = (unsigned short*)(w + 64 * MiB);  // 16 MiB [dies after Gatt]
  unsigned short* att_bf  = (unsigned short*)(w + 64 * MiB);  //  8 MiB (reuses k)
  unsigned short* vt_bf   = (unsigned short*)(w + 80 * MiB);  // 16 MiB
  unsigned short* Tx2_bf  = (unsigned short*)(w + 96 * MiB);  // 16 MiB
  unsigned short* lw_bf   = (unsigned short*)(w + 112 * MiB); // 0.5 MiB
  unsigned short* qw_bf   = (unsigned short*)(w + 113 * MiB); // 2 MiB \ adjacent: one
  unsigned short* kw_bf   = (unsigned short*)(w + 115 * MiB); // 2 MiB / [2048,1024] matrix
  unsigned short* vw_bf   = (unsigned short*)(w + 117 * MiB); // 2 MiB
  float*          dis     = (float*)(w + 119 * MiB);          // 64 KiB

  // casts to bf16
  cast_kernel<<<(B * N * C / 4 + 255) / 256, 256, 0, stream>>>(node_feats, nf_bf, B * N * C / 4);
  cast_kernel<<<(C * C / 4 + 255) / 256, 256, 0, stream>>>(linear_w, lw_bf, C * C / 4);
  cast_kernel<<<(N * N / 4 + 255) / 256, 256, 0, stream>>>(q_w, qw_bf, N * N / 4);
  cast_kernel<<<(N * N / 4 + 255) / 256, 256, 0, stream>>>(k_w, kw_bf, N * N / 4);
  cast_kernel<<<(N * N / 4 + 255) / 256, 256, 0, stream>>>(v_w, vw_bf, N * N / 4);

  // degree normalization factors
  sigrow_kernel<<<B * N, 256, 0, stream>>>(adj, edge, dis);

  // G1: Xt[b,o,n] = leaky(lw @ nf^T + lb[o])   M=C, Nc=N, K=C  gx=8 gy=4
  gemm_bt<1, true, false, false, false><<<512, 256, 0, stream>>>(
      lw_bf, 0, nf_bf, (size_t)N * C, linear_b, nullptr, nullptr,
      Xt_bf, nullptr, C, N, C, 3, 2, 999);

  // LN1 over n (D=1024) -> Txln bf16
  ln_kernel<4, false><<<B * C, 256, 0, stream>>>(Xt_bf, n1w, n1b, Txln, N);

  // fused q|k: [b,x,g] = Txln @ [qw;kw]^T + [qb;kb]   M=C, Nc=2048, K=N
  // gx=16 gy=4; x<8 -> q, x>=8 -> k (out2/bias2 pre-shifted by -1024 cols)
  gemm_bt<2, false, false, false, true><<<1024, 256, 0, stream>>>(
      Txln, (size_t)C * N, qw_bf, 0, q_b, k_b - 1024, nullptr,
      q_bf, (void*)(k_bf - 1024), C, N, N, 4, 2, 8);

  // v^T: vt[b,g,x] = leaky(v_w @ Txln^T + v_b[g])   M=N, Nc=C, K=N  gx=4 gy=8
  gemm_bt<1, true, false, false, false><<<512, 256, 0, stream>>>(
      vw_bf, 0, Txln, (size_t)C * N, v_b, nullptr, nullptr,
      vt_bf, nullptr, N, C, N, 2, 3, 999);

  // att_raw[b,x,y] = q @ k^T   M=C, Nc=C, K=N   (f32 out)  gx=4 gy=4
  gemm_bt<0, false, false, true, false><<<256, 256, 0, stream>>>(
      q_bf, (size_t)C * N, k_bf, (size_t)C * N, nullptr, nullptr, nullptr,
      att_raw, nullptr, C, C, N, 2, 2, 999);

  // softmax(att_raw * 1/32) -> att_bf
  softmax_kernel<<<B * C, 256, 0, stream>>>(att_raw, att_bf);

  // W_A normalized bf16 (overwrites bytes [0,32MiB): nf/att_raw/Xt all dead)
  wa_kernel<<<B * N * N / 4 / 256, 256, 0, stream>>>(adj, edge, dis, WA_bf);

  // Tx2[b,x,h] = Txln + att @ v    M=C, Nc=N, K=C   (Bt = vt)  gx=8 gy=4
  gemm_bt<0, false, true, false, false><<<512, 256, 0, stream>>>(
      att_bf, (size_t)C * C, vt_bf, (size_t)N * C, nullptr, nullptr, Txln,
      Tx2_bf, nullptr, C, N, C, 3, 2, 999);

  // X3[b,n,o] = W_A @ X2          M=N, Nc=C, K=N   (Bt = Tx2)  gx=4 gy=8
  gemm_bt<0, false, false, false, false><<<512, 256, 0, stream>>>(
      WA_bf, (size_t)N * N, Tx2_bf, (size_t)C * N, nullptr, nullptr, nullptr,
      X3_bf, nullptr, N, C, N, 2, 3, 999);

  // final LN over o (D=512) -> f32 out
  ln_kernel<2, true><<<B * N, 256, 0, stream>>>(X3_bf, n2w, n2b, out, C);
}